// Round 9
// baseline (169.531 us; speedup 1.0000x reference)
//
#include <hip/hip_runtime.h>
#include <hip/hip_bf16.h>

typedef _Float16 half8 __attribute__((ext_vector_type(8)));
typedef _Float16 half4 __attribute__((ext_vector_type(4)));
typedef float f32x4 __attribute__((ext_vector_type(4)));

namespace {

constexpr int INW  = 87;
constexpr int ROWS = 64;    // rows per block
constexpr int NT   = 512;   // 8 waves, each owns a 32-col stripe, all 64 rows

// ws layout (fp16 halves), n-major [256][Kpad], all 16B aligned
constexpr long O_WE  = 0;       // [256][96]: k<77 fold(Wfc1@Wenc), k==77 bias row
constexpr long O_WD  = 24576;   // [256][32]: k<10 fold(Wfc2@Wdec), k==10 bias row
constexpr long O_HDS = 32768;   // 8 x [256][256], then fc3 contiguous at +8*65536
constexpr long O_FC3 = 557056;  // = O_HDS + 8*65536
constexpr long CONV_TOTAL = 589824;  // halves for hds+fc3

__device__ __forceinline__ int aidx(int row, int col) {
  return row * 256 + ((((col >> 3) ^ (row & 7)) << 3) | (col & 7));
}

// ---------------- prep: fold enc chain:  WE[n][k] ----------------
__global__ __launch_bounds__(256)
void prep_fold_enc(const float* __restrict__ Wfc1, const float* __restrict__ bfc1,
                   const float* __restrict__ Wenc, const float* __restrict__ benc,
                   _Float16* __restrict__ ws)
{
  const int t = (int)blockIdx.x * 256 + (int)threadIdx.x;   // 96*256 threads
  const int n = t & 255, k = t >> 8;                        // k 0..95
  float acc = 0.f;
  if (k < 77) {
    for (int m = 0; m < 256; ++m) acc += Wfc1[(size_t)k * 256 + m] * Wenc[(size_t)m * 256 + n];
  } else if (k == 77) {
    for (int m = 0; m < 256; ++m) acc += bfc1[m] * Wenc[(size_t)m * 256 + n];
    acc += benc[n];
  }
  ws[O_WE + (long)n * 96 + k] = (_Float16)acc;
}

// ---------------- prep: fold dec chain:  WD[n][k] ----------------
__global__ __launch_bounds__(256)
void prep_fold_dec(const float* __restrict__ Wfc2, const float* __restrict__ bfc2,
                   const float* __restrict__ Wdec, const float* __restrict__ bdec,
                   _Float16* __restrict__ ws)
{
  const int t = (int)blockIdx.x * 256 + (int)threadIdx.x;   // 32*256 threads
  const int n = t & 255, k = t >> 8;                        // k 0..31
  float acc = 0.f;
  if (k < 10) {
    for (int m = 0; m < 256; ++m) acc += Wfc2[(size_t)k * 256 + m] * Wdec[(size_t)m * 256 + n];
  } else if (k == 10) {
    for (int m = 0; m < 256; ++m) acc += bfc2[m] * Wdec[(size_t)m * 256 + n];
    acc += bdec[n];
  }
  ws[O_WD + (long)n * 32 + k] = (_Float16)acc;
}

// ---------------- prep: transpose+convert heads & fc3 ----------------
__global__ __launch_bounds__(256)
void prep_conv(const float* __restrict__ Whds, const float* __restrict__ Wfc3,
               _Float16* __restrict__ ws)
{
  const long t = (long)blockIdx.x * 256 + threadIdx.x;
  const long e = t * 4;
  if (e >= CONV_TOTAL) return;
  const int h = (int)(e >> 16);                 // 0..8 (8 == fc3)
  const float* src = (h < 8) ? (Whds + ((long)h << 16)) : Wfc3;
  const long le = e & 65535;
  const int n = (int)(le >> 8), k0 = (int)(le & 255);
  half4 v;
#pragma unroll
  for (int j = 0; j < 4; ++j)
    v[j] = (_Float16)src[(size_t)(k0 + j) * 256 + n];
  *(half4*)&ws[O_HDS + e] = v;
}

// lgkm-only barrier: LDS visibility without draining vmcnt (B prefetches
// stay in flight across it).
__device__ __forceinline__ void sync_lgkm() {
  asm volatile("s_waitcnt lgkmcnt(0)" ::: "memory");
  __builtin_amdgcn_s_barrier();
}

// =========================== main fused kernel ===========================
__global__ __launch_bounds__(NT)
__attribute__((amdgpu_waves_per_eu(2)))
void fused_mfma(const float* __restrict__ x,
                const float* __restrict__ bhds,
                const float* __restrict__ bfc3,
                const float* __restrict__ Wq,  const float* __restrict__ bq,
                const int* __restrict__ agent,
                const _Float16* __restrict__ ws,
                float* __restrict__ out)
{
  __shared__ _Float16 A[ROWS * 256];        // 32 KB
  __shared__ half4 decH[8][NT];             // 32 KB: dec_H, per-thread chunks
  __shared__ float sp[2][8][ROWS];          // 4 KB

  const int tid  = (int)threadIdx.x;
  const int lane = tid & 63;
  const int wn   = tid >> 6;        // 0..7 : this wave's 32-col stripe
  const int l15  = lane & 15;
  const int l4   = lane >> 4;
  const int cbase = wn * 32;
  const int row0 = (int)blockIdx.x * ROWS;
  const int a = agent[0];

  auto loadBraw = [&](const _Float16* b, int Klen, int k0, half8& qa, half8& qb) {
    const _Float16* p = b + (long)(cbase + l15) * Klen + k0 + (long)l4 * 8;
    qa = *(const half8*)p;
    qb = *(const half8*)(p + (long)16 * Klen);
  };
  // heads+fc3 region is contiguous: slice i in [4,76) -> matrix (i-4)>>3, k0=((i-4)&7)*32
  auto loadBH = [&](int i, half8& qa, half8& qb) {
    const int t = (i < 75 ? i : 75) - 4;
    loadBraw(ws + O_HDS + (long)(t >> 3) * 65536, 256, (t & 7) * 32, qa, qb);
  };
  auto loadBany = [&](int i, half8& qa, half8& qb) {
    if (i < 3)       loadBraw(ws + O_WE, 96, i * 32, qa, qb);
    else if (i == 3) loadBraw(ws + O_WD, 32, 0, qa, qb);
    else             loadBH(i, qa, qb);
  };
  auto ldAF = [&](half8 (&af4)[4], int acol) {
#pragma unroll
    for (int mt = 0; mt < 4; ++mt) {
      const int row = mt * 16 + l15;
      const int cch = (acol >> 3) + l4;
      af4[mt] = *(const half8*)&A[row * 256 + ((cch ^ (row & 7)) << 3)];
    }
  };
  auto mfma8 = [&](const half8 (&af4)[4], const half8& ba, const half8& bb,
                   f32x4 (&acc)[4][2]) {
#pragma unroll
    for (int mt = 0; mt < 4; ++mt) {
      acc[mt][0] = __builtin_amdgcn_mfma_f32_16x16x32_f16(af4[mt], ba, acc[mt][0], 0, 0, 0);
      acc[mt][1] = __builtin_amdgcn_mfma_f32_16x16x32_f16(af4[mt], bb, acc[mt][1], 0, 0, 0);
    }
  };
  auto zeroAcc = [&](f32x4 (&acc)[4][2]) {
#pragma unroll
    for (int mt = 0; mt < 4; ++mt)
#pragma unroll
      for (int nt = 0; nt < 2; ++nt) acc[mt][nt] = { 0.f, 0.f, 0.f, 0.f };
  };
  auto writeA = [&](const f32x4 (&acc)[4][2], bool relu) {
#pragma unroll
    for (int mt = 0; mt < 4; ++mt)
#pragma unroll
      for (int nt = 0; nt < 2; ++nt)
#pragma unroll
        for (int r = 0; r < 4; ++r) {
          float v = acc[mt][nt][r];
          if (relu) v = fmaxf(v, 0.f);
          A[aidx(mt * 16 + l4 * 4 + r, cbase + nt * 16 + l15)] = (_Float16)v;
        }
  };

  // ---- depth-2 B pipeline prologue ----
  half8 q0a, q0b, q1a, q1b;
  loadBany(0, q0a, q0b); loadBany(1, q1a, q1b);

  // ---- build A0 (cols 0..127): enc-in 0..76, 77=1, dec-others 96..105, 106=1 ----
  for (int i = tid; i < ROWS * 128; i += NT) {
    const int r = i >> 7, c = i & 127;
    float v = 0.f;
    const size_t xb = (size_t)(row0 + r) * INW;
    if (c < 72)            v = x[xb + c];
    else if (c < 77)       v = x[xb + 72 + 5 * a + (c - 72)];
    else if (c == 77)      v = 1.f;
    else if (c >= 96 && c < 106) {
      const int o = c - 96;
      v = x[xb + 72 + (o < 5 * a ? o : o + 5)];
    }
    else if (c == 106)     v = 1.f;
    A[aidx(r, c)] = (_Float16)v;
  }
  sync_lgkm();

  // ---- prologue GEMMs: enc pre-relu -> ctx regs ; dec pre-relu -> acc regs ----
  f32x4 ctx[4][2], acc[4][2];
  zeroAcc(ctx); zeroAcc(acc);
  {
    half8 t4[4];
    ldAF(t4, 0);  mfma8(t4, q0a, q0b, ctx); loadBany(2, q0a, q0b);
    ldAF(t4, 32); mfma8(t4, q1a, q1b, ctx); loadBany(3, q1a, q1b);
    ldAF(t4, 64); mfma8(t4, q0a, q0b, ctx); loadBany(4, q0a, q0b);
    ldAF(t4, 96); mfma8(t4, q1a, q1b, acc); loadBany(5, q1a, q1b);
  }

  // dec_H = relu(acc) -> LDS (fp16, per-thread chunks, [8][512] half4)
#pragma unroll
  for (int mt = 0; mt < 4; ++mt)
#pragma unroll
    for (int nt = 0; nt < 2; ++nt) {
      half4 d = { (_Float16)fmaxf(acc[mt][nt][0], 0.f),
                  (_Float16)fmaxf(acc[mt][nt][1], 0.f),
                  (_Float16)fmaxf(acc[mt][nt][2], 0.f),
                  (_Float16)fmaxf(acc[mt][nt][3], 0.f) };
      decH[mt * 2 + nt][tid] = d;
    }

  sync_lgkm();                        // A0 reads done; decH writes pending ok
  writeA(ctx, true);                  // A := enc_h = relu(enc pre-relu)
  zeroAcc(ctx);
  sync_lgkm();                        // enc_h + decH visible to all

  // ---- load A (enc_h) stationary into registers: af[8][4], 128 VGPRs ----
  half8 af[8][4];
#pragma unroll
  for (int ks = 0; ks < 8; ++ks) ldAF(af[ks], ks * 32);

  // ---- heads + online softmax (reference = head-0 score) ----
  float s0L = 0.f, lsumL = 1.f;       // softmax state for row == lane

  for (int h = 0; h < 8; ++h) {
    const int base = 4 + 8 * h;
    float bh0 = bhds[h * 256 + cbase + l15];
    float bh1 = bhds[h * 256 + cbase + 16 + l15];

    zeroAcc(acc);
    mfma8(af[0], q0a, q0b, acc); loadBH(base + 2, q0a, q0b);
    mfma8(af[1], q1a, q1b, acc); loadBH(base + 3, q1a, q1b);
    mfma8(af[2], q0a, q0b, acc); loadBH(base + 4, q0a, q0b);
    mfma8(af[3], q1a, q1b, acc); loadBH(base + 5, q1a, q1b);
    mfma8(af[4], q0a, q0b, acc); loadBH(base + 6, q0a, q0b);
    mfma8(af[5], q1a, q1b, acc); loadBH(base + 7, q1a, q1b);
    mfma8(af[6], q0a, q0b, acc); loadBH(base + 8, q0a, q0b);
    mfma8(af[7], q1a, q1b, acc); loadBH(base + 9, q1a, q1b);

    // bias + relu
#pragma unroll
    for (int mt = 0; mt < 4; ++mt)
#pragma unroll
      for (int r = 0; r < 4; ++r) {
        acc[mt][0][r] = fmaxf(acc[mt][0][r] + bh0, 0.f);
        acc[mt][1][r] = fmaxf(acc[mt][1][r] + bh1, 0.f);
      }

    // score partials over this wave's 32 cols (dec_H from LDS)
    float p[4][4];
#pragma unroll
    for (int mt = 0; mt < 4; ++mt) {
      const half4 d0 = decH[mt * 2 + 0][tid];
      const half4 d1 = decH[mt * 2 + 1][tid];
#pragma unroll
      for (int r = 0; r < 4; ++r)
        p[mt][r] = fmaf(acc[mt][0][r], (float)d0[r],
                        acc[mt][1][r] * (float)d1[r]);
    }
#pragma unroll
    for (int off = 1; off < 16; off <<= 1)
#pragma unroll
      for (int mt = 0; mt < 4; ++mt)
#pragma unroll
        for (int r = 0; r < 4; ++r)
          p[mt][r] += __shfl_xor(p[mt][r], off, 64);
    if (l15 == 0) {
#pragma unroll
      for (int mt = 0; mt < 4; ++mt)
#pragma unroll
        for (int r = 0; r < 4; ++r)
          sp[h & 1][wn][mt * 16 + l4 * 4 + r] = p[mt][r];
    }
    sync_lgkm();                      // sp[h&1] visible; B loads stay in flight

    // total score for row == lane (8 scalar LDS reads), softmax update
    float sh = 0.f;
#pragma unroll
    for (int w = 0; w < 8; ++w) sh += sp[h & 1][w][lane];
    float wL;
    if (h == 0) { s0L = sh; lsumL = 1.f; wL = 1.f; }
    else        { wL = __expf(fminf(sh - s0L, 70.f)); lsumL += wL; }

    // redistribute weight to the (mt,r) holders of each row
#pragma unroll
    for (int mt = 0; mt < 4; ++mt)
#pragma unroll
      for (int r = 0; r < 4; ++r) {
        const float wgt = __shfl(wL, mt * 16 + l4 * 4 + r, 64);
#pragma unroll
        for (int nt = 0; nt < 2; ++nt)
          ctx[mt][nt][r] = fmaf(wgt, acc[mt][nt][r], ctx[mt][nt][r]);
      }
    // sp[h&1] reused at h+2; fenced by head h+1's barrier
  }

  // normalize context (inv at row==lane, shfl out)
  {
    const float invL = 1.f / lsumL;
#pragma unroll
    for (int mt = 0; mt < 4; ++mt)
#pragma unroll
      for (int r = 0; r < 4; ++r) {
        const float inv = __shfl(invL, mt * 16 + l4 * 4 + r, 64);
#pragma unroll
        for (int nt = 0; nt < 2; ++nt) ctx[mt][nt][r] *= inv;
      }
  }
  writeA(ctx, false);                 // A := context (af regs hold enc_h; A free)
  sync_lgkm();

  // ---- reload A (ctx) into af regs, then fc3 (+bias+relu) @ Wq ----
#pragma unroll
  for (int ks = 0; ks < 8; ++ks) ldAF(af[ks], ks * 32);

  float bf30 = bfc3[cbase + l15],      bf31 = bfc3[cbase + 16 + l15];
  float wq0  = Wq[cbase + l15],        wq1  = Wq[cbase + 16 + l15];

  zeroAcc(acc);
  // entering: q0 = slice 68 (fc3 k0), q1 = slice 69 (loaded during head 7)
  mfma8(af[0], q0a, q0b, acc); loadBH(70, q0a, q0b);
  mfma8(af[1], q1a, q1b, acc); loadBH(71, q1a, q1b);
  mfma8(af[2], q0a, q0b, acc); loadBH(72, q0a, q0b);
  mfma8(af[3], q1a, q1b, acc); loadBH(73, q1a, q1b);
  mfma8(af[4], q0a, q0b, acc); loadBH(74, q0a, q0b);
  mfma8(af[5], q1a, q1b, acc); loadBH(75, q1a, q1b);
  mfma8(af[6], q0a, q0b, acc);
  mfma8(af[7], q1a, q1b, acc);

  float p[4][4];
#pragma unroll
  for (int mt = 0; mt < 4; ++mt)
#pragma unroll
    for (int r = 0; r < 4; ++r) {
      p[mt][r] = fmaf(fmaxf(acc[mt][0][r] + bf30, 0.f), wq0,
                      fmaxf(acc[mt][1][r] + bf31, 0.f) * wq1);
    }
#pragma unroll
  for (int off = 1; off < 16; off <<= 1)
#pragma unroll
    for (int mt = 0; mt < 4; ++mt)
#pragma unroll
      for (int r = 0; r < 4; ++r)
        p[mt][r] += __shfl_xor(p[mt][r], off, 64);
  if (l15 == 0) {
#pragma unroll
    for (int mt = 0; mt < 4; ++mt)
#pragma unroll
      for (int r = 0; r < 4; ++r)
        sp[0][wn][mt * 16 + l4 * 4 + r] = p[mt][r];
  }
  sync_lgkm();
  if (tid < ROWS) {
    float v = bq[0];
#pragma unroll
    for (int w = 0; w < 8; ++w) v += sp[0][w][tid];
    out[row0 + tid] = v;
  }
}

}  // namespace

extern "C" void kernel_launch(void* const* d_in, const int* in_sizes, int n_in,
                              void* d_out, int out_size, void* d_ws, size_t ws_size,
                              hipStream_t stream) {
  const float* x    = (const float*)d_in[0];
  const float* Wfc1 = (const float*)d_in[1];
  const float* bfc1 = (const float*)d_in[2];
  const float* Wfc2 = (const float*)d_in[3];
  const float* bfc2 = (const float*)d_in[4];
  const float* Wenc = (const float*)d_in[5];
  const float* benc = (const float*)d_in[6];
  const float* Whds = (const float*)d_in[7];
  const float* bhds = (const float*)d_in[8];
  const float* Wdec = (const float*)d_in[9];
  const float* bdec = (const float*)d_in[10];
  const float* Wfc3 = (const float*)d_in[11];
  const float* bfc3 = (const float*)d_in[12];
  const float* Wq   = (const float*)d_in[13];
  const float* bq   = (const float*)d_in[14];
  const int*  agent = (const int*)d_in[15];
  float* out = (float*)d_out;
  _Float16* ws = (_Float16*)d_ws;

  const int Bn = in_sizes[0] / INW;         // 32768
  const int grid = Bn / ROWS;               // 512 blocks

  prep_fold_enc<<<96, 256, 0, stream>>>(Wfc1, bfc1, Wenc, benc, ws);
  prep_fold_dec<<<32, 256, 0, stream>>>(Wfc2, bfc2, Wdec, bdec, ws);
  prep_conv<<<(int)((CONV_TOTAL / 4 + 255) / 256), 256, 0, stream>>>(Whds, Wfc3, ws);
  fused_mfma<<<grid, NT, 0, stream>>>(x, bhds, bfc3, Wq, bq, agent, ws, out);
}

// Round 10
// 143.328 us; speedup vs baseline: 1.1828x; 1.1828x over previous
//
#include <hip/hip_runtime.h>
#include <hip/hip_bf16.h>

typedef _Float16 half8 __attribute__((ext_vector_type(8)));
typedef _Float16 half4 __attribute__((ext_vector_type(4)));
typedef float f32x4 __attribute__((ext_vector_type(4)));

namespace {

constexpr int INW  = 87;
constexpr int ROWS = 64;    // rows per block
constexpr int NT   = 256;   // 4 waves; each wave: 64 rows x 64 cols

// ws layout (fp16 halves), n-major [256][Kpad], all 16B aligned
constexpr long O_WE  = 0;       // [256][96]: k<77 fold(Wfc1@Wenc), k==77 bias row
constexpr long O_WD  = 24576;   // [256][32]: k<10 fold(Wfc2@Wdec), k==10 bias row
constexpr long O_HDS = 32768;   // 8 x [256][256], fc3 contiguous after
constexpr long O_FC3 = 557056;  // = O_HDS + 8*65536
constexpr long CONV_TOTAL = 589824;

__device__ __forceinline__ int aidx(int row, int col) {
  return row * 256 + ((((col >> 3) ^ (row & 7)) << 3) | (col & 7));
}

// ---------------- prep: fold enc chain:  WE[n][k] ----------------
__global__ __launch_bounds__(256)
void prep_fold_enc(const float* __restrict__ Wfc1, const float* __restrict__ bfc1,
                   const float* __restrict__ Wenc, const float* __restrict__ benc,
                   _Float16* __restrict__ ws)
{
  const int t = (int)blockIdx.x * 256 + (int)threadIdx.x;   // 96*256 threads
  const int n = t & 255, k = t >> 8;                        // k 0..95
  float acc = 0.f;
  if (k < 77) {
    for (int m = 0; m < 256; ++m) acc += Wfc1[(size_t)k * 256 + m] * Wenc[(size_t)m * 256 + n];
  } else if (k == 77) {
    for (int m = 0; m < 256; ++m) acc += bfc1[m] * Wenc[(size_t)m * 256 + n];
    acc += benc[n];
  }
  ws[O_WE + (long)n * 96 + k] = (_Float16)acc;
}

// ---------------- prep: fold dec chain:  WD[n][k] ----------------
__global__ __launch_bounds__(256)
void prep_fold_dec(const float* __restrict__ Wfc2, const float* __restrict__ bfc2,
                   const float* __restrict__ Wdec, const float* __restrict__ bdec,
                   _Float16* __restrict__ ws)
{
  const int t = (int)blockIdx.x * 256 + (int)threadIdx.x;   // 32*256 threads
  const int n = t & 255, k = t >> 8;                        // k 0..31
  float acc = 0.f;
  if (k < 10) {
    for (int m = 0; m < 256; ++m) acc += Wfc2[(size_t)k * 256 + m] * Wdec[(size_t)m * 256 + n];
  } else if (k == 10) {
    for (int m = 0; m < 256; ++m) acc += bfc2[m] * Wdec[(size_t)m * 256 + n];
    acc += bdec[n];
  }
  ws[O_WD + (long)n * 32 + k] = (_Float16)acc;
}

// ---------------- prep: transpose+convert heads & fc3 ----------------
__global__ __launch_bounds__(256)
void prep_conv(const float* __restrict__ Whds, const float* __restrict__ Wfc3,
               _Float16* __restrict__ ws)
{
  const long t = (long)blockIdx.x * 256 + threadIdx.x;
  const long e = t * 4;
  if (e >= CONV_TOTAL) return;
  const int h = (int)(e >> 16);                 // 0..8 (8 == fc3)
  const float* src = (h < 8) ? (Whds + ((long)h << 16)) : Wfc3;
  const long le = e & 65535;
  const int n = (int)(le >> 8), k0 = (int)(le & 255);
  half4 v;
#pragma unroll
  for (int j = 0; j < 4; ++j)
    v[j] = (_Float16)src[(size_t)(k0 + j) * 256 + n];
  *(half4*)&ws[O_HDS + e] = v;
}

// lgkm-only barrier: LDS visibility; global (vmcnt) B loads stay in flight
__device__ __forceinline__ void sync_lgkm() {
  asm volatile("s_waitcnt lgkmcnt(0)" ::: "memory");
  __builtin_amdgcn_s_barrier();
}

typedef const __attribute__((address_space(1))) half8* gptr8;

// =========================== main fused kernel ===========================
__global__ __launch_bounds__(NT)
void fused_mfma(const float* __restrict__ x,
                const float* __restrict__ bhds,
                const float* __restrict__ bfc3,
                const float* __restrict__ Wq,  const float* __restrict__ bq,
                const int* __restrict__ agent,
                const _Float16* __restrict__ ws,
                float* __restrict__ out)
{
  __shared__ _Float16 A[ROWS * 256];        // 32 KB
  __shared__ float sp[2][4][ROWS];          // 2 KB

  const int tid  = (int)threadIdx.x;
  const int lane = tid & 63;
  const int wn   = tid >> 6;        // 0..3 : this wave's 64-col stripe
  const int l15  = lane & 15;
  const int l4   = lane >> 4;
  const int cbase = wn * 64;
  const int row0 = (int)blockIdx.x * ROWS;
  const int a = agent[0];

  // B load: 4 half8 (one per 16-col group) of a 32-k slice, forced global
  auto loadBraw = [&](const _Float16* b, int Klen, int k0, half8 (&q)[4]) {
#pragma unroll
    for (int nt = 0; nt < 4; ++nt) {
      const _Float16* p = b + (long)(cbase + nt * 16 + l15) * Klen + k0 + (long)l4 * 8;
      q[nt] = *(gptr8)p;
    }
  };
  // heads+fc3 contiguous region: slice i in [4,76) -> matrix (i-4)>>3
  auto loadBH = [&](int i, half8 (&q)[4]) {
    const int t = (i < 75 ? i : 75) - 4;
    loadBraw(ws + O_HDS + (long)(t >> 3) * 65536, 256, (t & 7) * 32, q);
  };
  auto loadBany = [&](int i, half8 (&q)[4]) {
    if (i < 3)       loadBraw(ws + O_WE, 96, i * 32, q);
    else if (i == 3) loadBraw(ws + O_WD, 32, 0, q);
    else             loadBH(i, q);
  };
  auto ldAF = [&](half8 (&af)[4], int acol) {
#pragma unroll
    for (int mt = 0; mt < 4; ++mt) {
      const int row = mt * 16 + l15;
      const int cch = (acol >> 3) + l4;
      af[mt] = *(const half8*)&A[row * 256 + ((cch ^ (row & 7)) << 3)];
    }
  };
  auto mfma16 = [&](const half8 (&af)[4], const half8 (&q)[4], f32x4 (&acc)[4][4]) {
#pragma unroll
    for (int mt = 0; mt < 4; ++mt)
#pragma unroll
      for (int nt = 0; nt < 4; ++nt)
        acc[mt][nt] = __builtin_amdgcn_mfma_f32_16x16x32_f16(af[mt], q[nt], acc[mt][nt], 0, 0, 0);
  };
  auto zeroAcc = [&](f32x4 (&acc)[4][4]) {
#pragma unroll
    for (int mt = 0; mt < 4; ++mt)
#pragma unroll
      for (int nt = 0; nt < 4; ++nt) acc[mt][nt] = { 0.f, 0.f, 0.f, 0.f };
  };
  auto writeA = [&](const f32x4 (&acc)[4][4], bool relu) {
#pragma unroll
    for (int mt = 0; mt < 4; ++mt)
#pragma unroll
      for (int nt = 0; nt < 4; ++nt)
#pragma unroll
        for (int r = 0; r < 4; ++r) {
          float v = acc[mt][nt][r];
          if (relu) v = fmaxf(v, 0.f);
          A[aidx(mt * 16 + l4 * 4 + r, cbase + nt * 16 + l15)] = (_Float16)v;
        }
  };

  // ---- depth-2 B pipeline prologue ----
  half8 q0[4], q1[4];
  loadBany(0, q0); loadBany(1, q1);

  // ---- build A0 (cols 0..127): enc-in 0..76, 77=1, dec-others 96..105, 106=1 ----
  for (int i = tid; i < ROWS * 128; i += NT) {
    const int r = i >> 7, c = i & 127;
    float v = 0.f;
    const size_t xb = (size_t)(row0 + r) * INW;
    if (c < 72)            v = x[xb + c];
    else if (c < 77)       v = x[xb + 72 + 5 * a + (c - 72)];
    else if (c == 77)      v = 1.f;
    else if (c >= 96 && c < 106) {
      const int o = c - 96;
      v = x[xb + 72 + (o < 5 * a ? o : o + 5)];
    }
    else if (c == 106)     v = 1.f;
    A[aidx(r, c)] = (_Float16)v;
  }
  sync_lgkm();

  // ---- prologue GEMMs: enc pre-relu -> ctx ; dec pre-relu -> acc ----
  f32x4 ctx[4][4], acc[4][4];
  zeroAcc(ctx); zeroAcc(acc);
  {
    half8 afA[4], afB[4];
    ldAF(afA, 0);  mfma16(afA, q0, ctx); loadBany(2, q0);
    ldAF(afB, 32); mfma16(afB, q1, ctx); loadBany(3, q1);
    ldAF(afA, 64); mfma16(afA, q0, ctx); loadBany(4, q0);
    ldAF(afB, 96); mfma16(afB, q1, acc); loadBany(5, q1);
  }

  // dec_H = relu -> packed fp16 in regs (same (mt,nt,r) positions as acc)
  half4 dpk[4][4];
#pragma unroll
  for (int mt = 0; mt < 4; ++mt)
#pragma unroll
    for (int nt = 0; nt < 4; ++nt)
      dpk[mt][nt] = half4{ (_Float16)fmaxf(acc[mt][nt][0], 0.f),
                           (_Float16)fmaxf(acc[mt][nt][1], 0.f),
                           (_Float16)fmaxf(acc[mt][nt][2], 0.f),
                           (_Float16)fmaxf(acc[mt][nt][3], 0.f) };

  sync_lgkm();                        // A0 reads done
  writeA(ctx, true);                  // A := enc_h = relu(enc pre-relu)
  zeroAcc(ctx);
  sync_lgkm();                        // enc_h visible

  // ---- heads + online softmax (reference = head-0 score) ----
  float s0L = 0.f, lsumL = 1.f;       // softmax state for row == lane

  for (int h = 0; h < 8; ++h) {
    const int base = 4 + 8 * h;
    float bh[4];
#pragma unroll
    for (int nt = 0; nt < 4; ++nt) bh[nt] = bhds[h * 256 + cbase + nt * 16 + l15];

    zeroAcc(acc);
    {
      half8 afA[4], afB[4];
      ldAF(afA, 0);   mfma16(afA, q0, acc); loadBH(base + 2, q0);
      ldAF(afB, 32);  mfma16(afB, q1, acc); loadBH(base + 3, q1);
      ldAF(afA, 64);  mfma16(afA, q0, acc); loadBH(base + 4, q0);
      ldAF(afB, 96);  mfma16(afB, q1, acc); loadBH(base + 5, q1);
      ldAF(afA, 128); mfma16(afA, q0, acc); loadBH(base + 6, q0);
      ldAF(afB, 160); mfma16(afB, q1, acc); loadBH(base + 7, q1);
      ldAF(afA, 192); mfma16(afA, q0, acc); loadBH(base + 8, q0);
      ldAF(afB, 224); mfma16(afB, q1, acc); loadBH(base + 9, q1);
    }

    // bias + relu, then score partials over this wave's 64 cols
    float p[4][4];
#pragma unroll
    for (int mt = 0; mt < 4; ++mt)
#pragma unroll
      for (int r = 0; r < 4; ++r) {
        float v = 0.f;
#pragma unroll
        for (int nt = 0; nt < 4; ++nt) {
          acc[mt][nt][r] = fmaxf(acc[mt][nt][r] + bh[nt], 0.f);
          v = fmaf(acc[mt][nt][r], (float)dpk[mt][nt][r], v);
        }
        p[mt][r] = v;
      }
#pragma unroll
    for (int off = 1; off < 16; off <<= 1)
#pragma unroll
      for (int mt = 0; mt < 4; ++mt)
#pragma unroll
        for (int r = 0; r < 4; ++r)
          p[mt][r] += __shfl_xor(p[mt][r], off, 64);
    if (l15 == 0) {
#pragma unroll
      for (int mt = 0; mt < 4; ++mt)
#pragma unroll
        for (int r = 0; r < 4; ++r)
          sp[h & 1][wn][mt * 16 + l4 * 4 + r] = p[mt][r];
    }
    sync_lgkm();                      // sp visible; B loads stay in flight

    // total score for row == lane (4 scalar LDS reads), softmax update
    const float sh = sp[h & 1][0][lane] + sp[h & 1][1][lane]
                   + sp[h & 1][2][lane] + sp[h & 1][3][lane];
    float wL;
    if (h == 0) { s0L = sh; lsumL = 1.f; wL = 1.f; }
    else        { wL = __expf(fminf(sh - s0L, 70.f)); lsumL += wL; }

    // redistribute weight to the (mt,r) holders of each row
#pragma unroll
    for (int mt = 0; mt < 4; ++mt)
#pragma unroll
      for (int r = 0; r < 4; ++r) {
        const float wgt = __shfl(wL, mt * 16 + l4 * 4 + r, 64);
#pragma unroll
        for (int nt = 0; nt < 4; ++nt)
          ctx[mt][nt][r] = fmaf(wgt, acc[mt][nt][r], ctx[mt][nt][r]);
      }
    // sp[h&1] reused at h+2; fenced by head h+1's barrier
  }

  // normalize context
  {
    const float invL = 1.f / lsumL;
#pragma unroll
    for (int mt = 0; mt < 4; ++mt)
#pragma unroll
      for (int r = 0; r < 4; ++r) {
        const float inv = __shfl(invL, mt * 16 + l4 * 4 + r, 64);
#pragma unroll
        for (int nt = 0; nt < 4; ++nt) ctx[mt][nt][r] *= inv;
      }
  }
  writeA(ctx, false);                 // A := context (head-7 reads drained at its barrier)
  sync_lgkm();

  // ---- fc3 (+bias+relu) then @ Wq ----
  float bf3[4], wq[4];
#pragma unroll
  for (int nt = 0; nt < 4; ++nt) {
    bf3[nt] = bfc3[cbase + nt * 16 + l15];
    wq[nt]  = Wq[cbase + nt * 16 + l15];
  }
  zeroAcc(acc);
  {
    half8 afA[4], afB[4];
    // entering: q0 = slice 68 (fc3 k0), q1 = slice 69 (loaded during head 7)
    ldAF(afA, 0);   mfma16(afA, q0, acc); loadBH(70, q0);
    ldAF(afB, 32);  mfma16(afB, q1, acc); loadBH(71, q1);
    ldAF(afA, 64);  mfma16(afA, q0, acc); loadBH(72, q0);
    ldAF(afB, 96);  mfma16(afB, q1, acc); loadBH(73, q1);
    ldAF(afA, 128); mfma16(afA, q0, acc); loadBH(74, q0);
    ldAF(afB, 160); mfma16(afB, q1, acc); loadBH(75, q1);
    ldAF(afA, 192); mfma16(afA, q0, acc);
    ldAF(afB, 224); mfma16(afB, q1, acc);
  }

  float p[4][4];
#pragma unroll
  for (int mt = 0; mt < 4; ++mt)
#pragma unroll
    for (int r = 0; r < 4; ++r) {
      float v = 0.f;
#pragma unroll
      for (int nt = 0; nt < 4; ++nt)
        v = fmaf(fmaxf(acc[mt][nt][r] + bf3[nt], 0.f), wq[nt], v);
      p[mt][r] = v;
    }
#pragma unroll
  for (int off = 1; off < 16; off <<= 1)
#pragma unroll
    for (int mt = 0; mt < 4; ++mt)
#pragma unroll
      for (int r = 0; r < 4; ++r)
        p[mt][r] += __shfl_xor(p[mt][r], off, 64);
  if (l15 == 0) {
#pragma unroll
    for (int mt = 0; mt < 4; ++mt)
#pragma unroll
      for (int r = 0; r < 4; ++r)
        sp[0][wn][mt * 16 + l4 * 4 + r] = p[mt][r];
  }
  sync_lgkm();
  if (tid < ROWS) {
    out[row0 + tid] = bq[0] + sp[0][0][tid] + sp[0][1][tid]
                    + sp[0][2][tid] + sp[0][3][tid];
  }
}

}  // namespace

extern "C" void kernel_launch(void* const* d_in, const int* in_sizes, int n_in,
                              void* d_out, int out_size, void* d_ws, size_t ws_size,
                              hipStream_t stream) {
  const float* x    = (const float*)d_in[0];
  const float* Wfc1 = (const float*)d_in[1];
  const float* bfc1 = (const float*)d_in[2];
  const float* Wfc2 = (const float*)d_in[3];
  const float* bfc2 = (const float*)d_in[4];
  const float* Wenc = (const float*)d_in[5];
  const float* benc = (const float*)d_in[6];
  const float* Whds = (const float*)d_in[7];
  const float* bhds = (const float*)d_in[8];
  const float* Wdec = (const float*)d_in[9];
  const float* bdec = (const float*)d_in[10];
  const float* Wfc3 = (const float*)d_in[11];
  const float* bfc3 = (const float*)d_in[12];
  const float* Wq   = (const float*)d_in[13];
  const float* bq   = (const float*)d_in[14];
  const int*  agent = (const int*)d_in[15];
  float* out = (float*)d_out;
  _Float16* ws = (_Float16*)d_ws;

  const int Bn = in_sizes[0] / INW;         // 32768
  const int grid = Bn / ROWS;               // 512 blocks

  prep_fold_enc<<<96, 256, 0, stream>>>(Wfc1, bfc1, Wenc, benc, ws);
  prep_fold_dec<<<32, 256, 0, stream>>>(Wfc2, bfc2, Wdec, bdec, ws);
  prep_conv<<<(int)((CONV_TOTAL / 4 + 255) / 256), 256, 0, stream>>>(Whds, Wfc3, ws);
  fused_mfma<<<grid, NT, 0, stream>>>(x, bhds, bfc3, Wq, bq, agent, ws, out);
}

// Round 12
// 133.109 us; speedup vs baseline: 1.2736x; 1.0768x over previous
//
#include <hip/hip_runtime.h>
#include <hip/hip_bf16.h>

typedef _Float16 half8 __attribute__((ext_vector_type(8)));
typedef _Float16 half4 __attribute__((ext_vector_type(4)));
typedef float f32x4 __attribute__((ext_vector_type(4)));

namespace {

constexpr int INW  = 87;
constexpr int ROWS = 64;    // rows per block
constexpr int NT   = 256;   // 4 waves; wave tile = 64 rows x 64 cols
constexpr int NSLICES = 76; // 3(WE) + 1(WD) + 64(heads) + 8(fc3)

// ws layout (fp16 halves), n-major [256][Kpad], 16B aligned
constexpr long O_WE  = 0;       // [256][96]: k<77 fold(Wfc1@Wenc), k==77 bias row
constexpr long O_WD  = 24576;   // [256][32]: k<10 fold(Wfc2@Wdec), k==10 bias row
constexpr long O_HDS = 32768;   // 8 x [256][256], fc3 contiguous after
constexpr long O_FC3 = 557056;  // = O_HDS + 8*65536
constexpr long CONV_TOTAL = 589824;

__device__ __forceinline__ int aidx(int row, int col) {
  return row * 256 + ((((col >> 3) ^ (row & 7)) << 3) | (col & 7));
}

// ---------------- prep kernels (unchanged) ----------------
__global__ __launch_bounds__(256)
void prep_fold_enc(const float* __restrict__ Wfc1, const float* __restrict__ bfc1,
                   const float* __restrict__ Wenc, const float* __restrict__ benc,
                   _Float16* __restrict__ ws)
{
  const int t = (int)blockIdx.x * 256 + (int)threadIdx.x;
  const int n = t & 255, k = t >> 8;
  float acc = 0.f;
  if (k < 77) {
    for (int m = 0; m < 256; ++m) acc += Wfc1[(size_t)k * 256 + m] * Wenc[(size_t)m * 256 + n];
  } else if (k == 77) {
    for (int m = 0; m < 256; ++m) acc += bfc1[m] * Wenc[(size_t)m * 256 + n];
    acc += benc[n];
  }
  ws[O_WE + (long)n * 96 + k] = (_Float16)acc;
}

__global__ __launch_bounds__(256)
void prep_fold_dec(const float* __restrict__ Wfc2, const float* __restrict__ bfc2,
                   const float* __restrict__ Wdec, const float* __restrict__ bdec,
                   _Float16* __restrict__ ws)
{
  const int t = (int)blockIdx.x * 256 + (int)threadIdx.x;
  const int n = t & 255, k = t >> 8;
  float acc = 0.f;
  if (k < 10) {
    for (int m = 0; m < 256; ++m) acc += Wfc2[(size_t)k * 256 + m] * Wdec[(size_t)m * 256 + n];
  } else if (k == 10) {
    for (int m = 0; m < 256; ++m) acc += bfc2[m] * Wdec[(size_t)m * 256 + n];
    acc += bdec[n];
  }
  ws[O_WD + (long)n * 32 + k] = (_Float16)acc;
}

__global__ __launch_bounds__(256)
void prep_conv(const float* __restrict__ Whds, const float* __restrict__ Wfc3,
               _Float16* __restrict__ ws)
{
  const long t = (long)blockIdx.x * 256 + threadIdx.x;
  const long e = t * 4;
  if (e >= CONV_TOTAL) return;
  const int h = (int)(e >> 16);
  const float* src = (h < 8) ? (Whds + ((long)h << 16)) : Wfc3;
  const long le = e & 65535;
  const int n = (int)(le >> 8), k0 = (int)(le & 255);
  half4 v;
#pragma unroll
  for (int j = 0; j < 4; ++j)
    v[j] = (_Float16)src[(size_t)(k0 + j) * 256 + n];
  *(half4*)&ws[O_HDS + e] = v;
}

// lgkm-only barrier: LDS visibility; DMA B stages (vmcnt) stay in flight
__device__ __forceinline__ void sync_lgkm() {
  asm volatile("s_waitcnt lgkmcnt(0)" ::: "memory");
  __builtin_amdgcn_s_barrier();
}

struct SliceD { const _Float16* base; int Klen; int k0; };
__device__ __forceinline__ SliceD slice_desc(int i, const _Float16* ws) {
  if (i < 3)  return { ws + O_WE, 96, i * 32 };
  if (i == 3) return { ws + O_WD, 32, 0 };
  if (i < 68) { const int t = i - 4;
                return { ws + O_HDS + (long)(t >> 3) * 65536, 256, (t & 7) * 32 }; }
  return { ws + O_FC3, 256, (i - 68) * 32 };
}

// =========================== main fused kernel ===========================
__global__ __launch_bounds__(NT)
__attribute__((amdgpu_waves_per_eu(2)))
void fused_mfma(const float* __restrict__ x,
                const float* __restrict__ bhds,
                const float* __restrict__ bfc3,
                const float* __restrict__ Wq,  const float* __restrict__ bq,
                const int* __restrict__ agent,
                const _Float16* __restrict__ ws,
                float* __restrict__ out)
{
  __shared__ _Float16 A[ROWS * 256];        // 32 KB
  __shared__ _Float16 Bst[4][2][2048];      // 32 KB: per-wave double-buffered B slice
  __shared__ float sp[2][4][ROWS];          // 2 KB
  __shared__ float biasL[2560];             // 10 KB: bhds[2048], bfc3[256], Wq[256]

  const int tid  = (int)threadIdx.x;
  const int lane = tid & 63;
  const int wn   = tid >> 6;        // 0..3 : this wave's 64-col stripe
  const int l15  = lane & 15;
  const int l4   = lane >> 4;
  const int cbase = wn * 64;
  const int row0 = (int)blockIdx.x * ROWS;
  const int a = agent[0];

  // ---- wave-private B stage: 64 cols x 32 k fp16 (4 KB) via global_load_lds ----
  // physical 16B chunk p = c*4 + s ; slot s holds logical k-chunk j = s ^ swz(c)
  auto stage = [&](int i) {
    const SliceD d = slice_desc(i, ws);
    _Float16* dst = &Bst[wn][i & 1][0];
#pragma unroll
    for (int ii = 0; ii < 4; ++ii) {
      const int p = ii * 64 + lane;
      const int c = p >> 2;
      const int j = (p & 3) ^ (c & 3) ^ ((c >> 2) & 3);
      const _Float16* src = d.base + (long)(cbase + c) * d.Klen + d.k0 + j * 8;
      auto* gp = (const __attribute__((address_space(1))) unsigned int*)src;
      auto* lp = (__attribute__((address_space(3))) unsigned int*)(dst + ii * 512);
      __builtin_amdgcn_global_load_lds(gp, lp, 16, 0, 0);
    }
  };

  auto ldAF = [&](half8 (&af)[4], int acol) {
#pragma unroll
    for (int mt = 0; mt < 4; ++mt) {
      const int row = mt * 16 + l15;
      const int cch = (acol >> 3) + l4;
      af[mt] = *(const half8*)&A[row * 256 + ((cch ^ (row & 7)) << 3)];
    }
  };

  auto sliceCompute = [&](int s, int acol, f32x4 (&acc)[4][4]) {
    half8 af[4], bf[4];
    ldAF(af, acol);
    const _Float16* bb = &Bst[wn][s & 1][0];
#pragma unroll
    for (int nt = 0; nt < 4; ++nt) {
      const int c = nt * 16 + l15;
      const int j = l4 ^ (c & 3) ^ ((c >> 2) & 3);
      bf[nt] = *(const half8*)&bb[c * 32 + (j << 3)];
    }
#pragma unroll
    for (int mt = 0; mt < 4; ++mt)
#pragma unroll
      for (int nt = 0; nt < 4; ++nt)
        acc[mt][nt] = __builtin_amdgcn_mfma_f32_16x16x32_f16(af[mt], bf[nt], acc[mt][nt], 0, 0, 0);
  };

  auto zeroAcc = [&](f32x4 (&acc)[4][4]) {
#pragma unroll
    for (int mt = 0; mt < 4; ++mt)
#pragma unroll
      for (int nt = 0; nt < 4; ++nt) acc[mt][nt] = { 0.f, 0.f, 0.f, 0.f };
  };

  int gs = 0;   // global slice counter; invariant: stage(gs), stage(gs+1) issued
  auto runSlices = [&](int KS, int acol0, f32x4 (&acc)[4][4]) {
    for (int s = 0; s < KS; ++s) {
      if (gs == NSLICES - 1) asm volatile("s_waitcnt vmcnt(0)" ::: "memory");
      else                   asm volatile("s_waitcnt vmcnt(4)" ::: "memory");
      sliceCompute(gs, acol0 + s * 32, acc);
      // WAR fence: stage(gs+2) writes buffer (gs+2)&1 == gs&1 — the buffer
      // this slice just read. Drain this wave's ds_reads and pin the
      // schedule so the DMA cannot be hoisted into/above them.
      asm volatile("s_waitcnt lgkmcnt(0)" ::: "memory");
      __builtin_amdgcn_sched_barrier(0);
      if (gs + 2 < NSLICES) stage(gs + 2);
      ++gs;
    }
  };

  auto writeA = [&](const f32x4 (&acc)[4][4], bool relu) {
#pragma unroll
    for (int mt = 0; mt < 4; ++mt)
#pragma unroll
      for (int nt = 0; nt < 4; ++nt)
#pragma unroll
        for (int r = 0; r < 4; ++r) {
          float v = acc[mt][nt][r];
          if (relu) v = fmaxf(v, 0.f);
          A[aidx(mt * 16 + l4 * 4 + r, cbase + nt * 16 + l15)] = (_Float16)v;
        }
  };

  // ---- build A0 (cols 0..127): enc-in 0..76, 77=1, dec-others 96..105, 106=1 ----
  for (int i = tid; i < ROWS * 128; i += NT) {
    const int r = i >> 7, c = i & 127;
    float v = 0.f;
    const size_t xb = (size_t)(row0 + r) * INW;
    if (c < 72)            v = x[xb + c];
    else if (c < 77)       v = x[xb + 72 + 5 * a + (c - 72)];
    else if (c == 77)      v = 1.f;
    else if (c >= 96 && c < 106) {
      const int o = c - 96;
      v = x[xb + 72 + (o < 5 * a ? o : o + 5)];
    }
    else if (c == 106)     v = 1.f;
    A[aidx(r, c)] = (_Float16)v;
  }
  // ---- stage biases into LDS (keeps vmcnt ledger pure afterwards) ----
  for (int i = tid; i < 2560; i += NT) {
    float v;
    if (i < 2048)      v = bhds[i];
    else if (i < 2304) v = bfc3[i - 2048];
    else               v = Wq[i - 2304];
    biasL[i] = v;
  }
  // full drain once, then start the DMA pipeline
  asm volatile("s_waitcnt vmcnt(0) lgkmcnt(0)" ::: "memory");
  __builtin_amdgcn_s_barrier();
  stage(0); stage(1);

  // ---- prologue GEMMs: enc pre-relu -> ctx ; dec pre-relu -> acc ----
  f32x4 ctx[4][4], acc[4][4];
  zeroAcc(ctx); zeroAcc(acc);
  runSlices(3, 0, ctx);       // gs 0..2 : folded enc, A cols 0..95
  runSlices(1, 96, acc);      // gs 3    : folded dec, A col 96

  half4 dpk[4][4];            // dec_H = relu, packed fp16
#pragma unroll
  for (int mt = 0; mt < 4; ++mt)
#pragma unroll
    for (int nt = 0; nt < 4; ++nt)
      dpk[mt][nt] = half4{ (_Float16)fmaxf(acc[mt][nt][0], 0.f),
                           (_Float16)fmaxf(acc[mt][nt][1], 0.f),
                           (_Float16)fmaxf(acc[mt][nt][2], 0.f),
                           (_Float16)fmaxf(acc[mt][nt][3], 0.f) };

  sync_lgkm();                // all waves' A0 reads done
  writeA(ctx, true);          // A := enc_h = relu(enc pre-relu)
  zeroAcc(ctx);
  sync_lgkm();                // enc_h visible

  // ---- heads + online softmax (reference = head-0 score) ----
  float s0L = 0.f, lsumL = 1.f;   // softmax state for row == lane

  for (int h = 0; h < 8; ++h) {
    float bh[4];
#pragma unroll
    for (int nt = 0; nt < 4; ++nt) bh[nt] = biasL[h * 256 + cbase + nt * 16 + l15];

    zeroAcc(acc);
    runSlices(8, 0, acc);     // gs 4+8h .. 11+8h

    // bias + relu, then score partials over this wave's 64 cols
    float p[4][4];
#pragma unroll
    for (int mt = 0; mt < 4; ++mt)
#pragma unroll
      for (int r = 0; r < 4; ++r) {
        float v = 0.f;
#pragma unroll
        for (int nt = 0; nt < 4; ++nt) {
          acc[mt][nt][r] = fmaxf(acc[mt][nt][r] + bh[nt], 0.f);
          v = fmaf(acc[mt][nt][r], (float)dpk[mt][nt][r], v);
        }
        p[mt][r] = v;
      }
#pragma unroll
    for (int off = 1; off < 16; off <<= 1)
#pragma unroll
      for (int mt = 0; mt < 4; ++mt)
#pragma unroll
        for (int r = 0; r < 4; ++r)
          p[mt][r] += __shfl_xor(p[mt][r], off, 64);
    if (l15 == 0) {
#pragma unroll
      for (int mt = 0; mt < 4; ++mt)
#pragma unroll
        for (int r = 0; r < 4; ++r)
          sp[h & 1][wn][mt * 16 + l4 * 4 + r] = p[mt][r];
    }
    sync_lgkm();              // sp visible; DMA stages stay in flight

    const float sh = sp[h & 1][0][lane] + sp[h & 1][1][lane]
                   + sp[h & 1][2][lane] + sp[h & 1][3][lane];
    float wL;
    if (h == 0) { s0L = sh; lsumL = 1.f; wL = 1.f; }
    else        { wL = __expf(fminf(sh - s0L, 70.f)); lsumL += wL; }

#pragma unroll
    for (int mt = 0; mt < 4; ++mt)
#pragma unroll
      for (int r = 0; r < 4; ++r) {
        const float wgt = __shfl(wL, mt * 16 + l4 * 4 + r, 64);
#pragma unroll
        for (int nt = 0; nt < 4; ++nt)
          ctx[mt][nt][r] = fmaf(wgt, acc[mt][nt][r], ctx[mt][nt][r]);
      }
    // sp[h&1] reused at h+2; fenced by head h+1's barrier
  }

  // normalize context
  {
    const float invL = 1.f / lsumL;
#pragma unroll
    for (int mt = 0; mt < 4; ++mt)
#pragma unroll
      for (int r = 0; r < 4; ++r) {
        const float inv = __shfl(invL, mt * 16 + l4 * 4 + r, 64);
#pragma unroll
        for (int nt = 0; nt < 4; ++nt) ctx[mt][nt][r] *= inv;
      }
  }
  writeA(ctx, false);         // A := context (head-7 reads fenced by its barrier)
  sync_lgkm();

  // ---- fc3 (+bias+relu) then @ Wq ----
  float bf3[4], wq[4];
#pragma unroll
  for (int nt = 0; nt < 4; ++nt) {
    bf3[nt] = biasL[2048 + cbase + nt * 16 + l15];
    wq[nt]  = biasL[2304 + cbase + nt * 16 + l15];
  }
  zeroAcc(acc);
  runSlices(8, 0, acc);       // gs 68..75 (last slice drains vmcnt to 0)

  float p[4][4];
#pragma unroll
  for (int mt = 0; mt < 4; ++mt)
#pragma unroll
    for (int r = 0; r < 4; ++r) {
      float v = 0.f;
#pragma unroll
      for (int nt = 0; nt < 4; ++nt)
        v = fmaf(fmaxf(acc[mt][nt][r] + bf3[nt], 0.f), wq[nt], v);
      p[mt][r] = v;
    }
#pragma unroll
  for (int off = 1; off < 16; off <<= 1)
#pragma unroll
    for (int mt = 0; mt < 4; ++mt)
#pragma unroll
      for (int r = 0; r < 4; ++r)
        p[mt][r] += __shfl_xor(p[mt][r], off, 64);
  if (l15 == 0) {
#pragma unroll
    for (int mt = 0; mt < 4; ++mt)
#pragma unroll
      for (int r = 0; r < 4; ++r)
        sp[0][wn][mt * 16 + l4 * 4 + r] = p[mt][r];
  }
  sync_lgkm();
  if (tid < ROWS) {
    out[row0 + tid] = bq[0] + sp[0][0][tid] + sp[0][1][tid]
                    + sp[0][2][tid] + sp[0][3][tid];
  }
}

}  // namespace

extern "C" void kernel_launch(void* const* d_in, const int* in_sizes, int n_in,
                              void* d_out, int out_size, void* d_ws, size_t ws_size,
                              hipStream_t stream) {
  const float* x    = (const float*)d_in[0];
  const float* Wfc1 = (const float*)d_in[1];
  const float* bfc1 = (const float*)d_in[2];
  const float* Wfc2 = (const float*)d_in[3];
  const float* bfc2 = (const float*)d_in[4];
  const float* Wenc = (const float*)d_in[5];
  const float* benc = (const float*)d_in[6];
  const float* Whds = (const float*)d_in[7];
  const float* bhds = (const float*)d_in[8];
  const float* Wdec = (const float*)d_in[9];
  const float* bdec = (const float*)d_in[10];
  const float* Wfc3 = (const float*)d_in[11];
  const float* bfc3 = (const float*)d_in[12];
  const float* Wq   = (const float*)d_in[13];
  const float* bq   = (const float*)d_in[14];
  const int*  agent = (const int*)d_in[15];
  float* out = (float*)d_out;
  _Float16* ws = (_Float16*)d_ws;

  const int Bn = in_sizes[0] / INW;         // 32768
  const int grid = Bn / ROWS;               // 512 blocks = 2 per CU, all resident

  prep_fold_enc<<<96, 256, 0, stream>>>(Wfc1, bfc1, Wenc, benc, ws);
  prep_fold_dec<<<32, 256, 0, stream>>>(Wfc2, bfc2, Wdec, bdec, ws);
  prep_conv<<<(int)((CONV_TOTAL / 4 + 255) / 256), 256, 0, stream>>>(Whds, Wfc3, ws);
  fused_mfma<<<grid, NT, 0, stream>>>(x, bhds, bfc3, Wq, bq, agent, ws, out);
}